// Round 1
// 828.828 us; speedup vs baseline: 1.0420x; 1.0420x over previous
//
#include <hip/hip_runtime.h>

// Problem constants
#define BATCH 1024
#define TT 48          // inst columns
#define NSTEP 47       // scan steps
#define VOC 2001       // V+1
#define RNN 64
#define NOBJ 25
#define NROWS (BATCH*NSTEP)   // 48128
#define NTILE 126             // ceil(2016/16)
#define NPAD 2016

typedef _Float16 h2 __attribute__((ext_vector_type(2)));
typedef _Float16 h8 __attribute__((ext_vector_type(8)));
typedef short short8 __attribute__((ext_vector_type(8)));
typedef float f32x4 __attribute__((ext_vector_type(4)));

__device__ __forceinline__ float fdot2f(h2 a, h2 b, float c){
#if __has_builtin(__builtin_amdgcn_fdot2)
    return __builtin_amdgcn_fdot2(a, b, c, false);
#else
    return c + (float)a[0]*(float)b[0] + (float)a[1]*(float)b[1];
#endif
}

__device__ __forceinline__ float dot8(h8 w, h8 x, float acc){
    acc = fdot2f(__builtin_shufflevector(w,w,0,1), __builtin_shufflevector(x,x,0,1), acc);
    acc = fdot2f(__builtin_shufflevector(w,w,2,3), __builtin_shufflevector(x,x,2,3), acc);
    acc = fdot2f(__builtin_shufflevector(w,w,4,5), __builtin_shufflevector(x,x,4,5), acc);
    acc = fdot2f(__builtin_shufflevector(w,w,6,7), __builtin_shufflevector(x,x,6,7), acc);
    return acc;
}

__device__ __forceinline__ float sigf(float x){ return 1.f/(1.f+__expf(-x)); }
__device__ __forceinline__ float tanh_(float x){
    float e = __expf(2.f*fminf(x, 15.f));   // clamp avoids inf/inf NaN
    return (e-1.f)/(e+1.f);
}
__device__ __forceinline__ unsigned short bf16r(float f){
    unsigned u = __float_as_uint(f);
    return (unsigned short)((u + 0x7FFFu + ((u>>16)&1u)) >> 16);
}

// LDS-only barrier: publishes ds_writes (lgkmcnt) but does NOT drain vmcnt,
// so embW prefetch / weight re-streams / h_hist stores pipeline across it.
// No cross-thread communication through global memory happens inside the
// recurrent loop, so skipping the vmcnt(0) drain is safe.
__device__ __forceinline__ void block_sync_lds(){
    asm volatile("s_waitcnt lgkmcnt(0)" ::: "memory");
    __builtin_amdgcn_s_barrier();
    asm volatile("" ::: "memory");
}

// ---------------------------------------------------------------- prep kernels

// diff_canvas + time-invariant attention terms pre1/pre2 [B,25,32]
__global__ void k_pre(const float* __restrict__ prev, const float* __restrict__ fin,
                      const float* __restrict__ a1w1, const float* __restrict__ a1b1,
                      const float* __restrict__ a2w1, const float* __restrict__ a2b1,
                      float* __restrict__ diff, float* __restrict__ pre1, float* __restrict__ pre2){
    int idx = blockIdx.x*256 + threadIdx.x;
    if (idx >= BATCH*NOBJ) return;
    float p0 = prev[idx*4+0], p1 = prev[idx*4+1], p2 = prev[idx*4+2], p3 = prev[idx*4+3];
    bool masked = (p0+p1+p2+p3) > 0.f;
    float d0 = masked ? -1.f : fin[idx*4+0];
    float d1 = masked ? -1.f : fin[idx*4+1];
    float d2 = masked ? -1.f : fin[idx*4+2];
    float d3 = masked ? -1.f : fin[idx*4+3];
    diff[idx*4+0]=d0; diff[idx*4+1]=d1; diff[idx*4+2]=d2; diff[idx*4+3]=d3;
    for (int j=0;j<32;++j){
        const float* w1 = a1w1 + j*68 + 64;
        const float* w2 = a2w1 + j*68 + 64;
        pre1[idx*32+j] = a1b1[j] + d0*w1[0] + d1*w1[1] + d2*w1[2] + d3*w1[3];
        pre2[idx*32+j] = a2b1[j] + p0*w2[0] + p1*w2[1] + p2*w2[2] + p3*w2[3];
    }
}

// embW[v][g] = b_ih_att[g]+b_hh_att[g] + sum_k embed[v][k]*W_ih_att[g][64+k]
__global__ void k_embw(const float* __restrict__ embed, const float* __restrict__ Wia,
                       const float* __restrict__ bia, const float* __restrict__ bha,
                       float* __restrict__ embW){
    int v = blockIdx.x, g = threadIdx.x;
    __shared__ float er[64];
    if (g < 64) er[g] = embed[v*64+g];
    __syncthreads();
    float acc = bia[g] + bha[g];
    const float* wr = Wia + g*128 + 64;
    #pragma unroll 8
    for (int k=0;k<64;++k) acc += er[k]*wr[k];
    embW[v*256+g] = acc;
}

// pack fp32 weight rows [G][srcK] cols koff..koff+K-1 -> f16 row-major [G][K]
__global__ void k_packrow(const float* __restrict__ src, _Float16* __restrict__ dst,
                          int srcK, int koff, int K, int total){
    int idx = blockIdx.x*256 + threadIdx.x;
    if (idx >= total) return;
    int k = idx % K, g = idx / K;
    dst[idx] = (_Float16)src[g*srcK + koff + k];
}

// Weff[g][m] = sum_d W_ih_lang[g][d]*tw2[d][m]; biasL2[g] = bil+bhl+sum_d W[g][d]*tb2[d]
__global__ void k_weff(const float* __restrict__ Wil, const float* __restrict__ tw2,
                       const float* __restrict__ tb2, const float* __restrict__ bil,
                       const float* __restrict__ bhl, _Float16* __restrict__ Weff,
                       float* __restrict__ biasL2){
    __shared__ float t2[64*32];
    int g = threadIdx.x;
    for (int i=g;i<2048;i+=256) t2[i] = tw2[i];
    __syncthreads();
    float accs[32];
    #pragma unroll
    for (int m=0;m<32;++m) accs[m]=0.f;
    float bf = bil[g] + bhl[g];
    for (int d=0;d<64;++d){
        float w = Wil[g*128 + d];
        bf += w * tb2[d];
        #pragma unroll
        for (int m=0;m<32;++m) accs[m] += w * t2[d*32+m];
    }
    #pragma unroll
    for (int m=0;m<32;++m) Weff[g*32+m] = (_Float16)accs[m];
    biasL2[g] = bf;
}

__global__ void k_fcbpad(const float* __restrict__ fcb_in, float* __restrict__ fcb){
    int i = blockIdx.x*256 + threadIdx.x;
    if (i >= NPAD) return;
    fcb[i] = (i < VOC) ? fcb_in[i] : -1e30f;
}

// fc_out_w -> bf16 MFMA B-fragment layout: [tile][khalf][lane][8]
__global__ void k_fragb(const float* __restrict__ fcw, unsigned short* __restrict__ fragB){
    int idx = blockIdx.x*256 + threadIdx.x;   // 126*2*64 = 16128
    int lane = idx & 63, kh = (idx>>6)&1, tile = idx>>7;
    int n = tile*16 + (lane & 15);
    int k = kh*32 + (lane >> 4)*8;
    unsigned short* d = fragB + (size_t)((tile*2+kh)*64 + lane)*8;
    #pragma unroll
    for (int i=0;i<8;++i)
        d[i] = (n < VOC) ? bf16r(fcw[n*64 + k + i]) : (unsigned short)0;
}

// ---------------------------------------------------------------- recurrent kernel
// 2 batch rows per block, 256 threads, 512 blocks (2 blocks/CU).
// Thread g=tid owns gate-row weights (shared by both rows). Per step only 4
// lgkm-only barriers:
//   P1 (all)   : att gates rows 0/1 + lang hl-partial        -> B1
//   P2 (wave r): LSTM-att update, h-proj, scores, softmax,
//                trans1 for row r, chained via intra-wave
//                in-order LDS (no block barrier needed)      -> B2
//   P3 (all)   : lang gates rows 0/1                         -> B3
//   P4 (wave r): LSTM-lang update + h_hist store             -> B4
__global__ __launch_bounds__(256, 2) void k_recur(
    const int* __restrict__ inst, const float* __restrict__ embW,
    const float* __restrict__ diff, const float* __restrict__ prev,
    const float* __restrict__ pre1, const float* __restrict__ pre2,
    const _Float16* __restrict__ attLp, const _Float16* __restrict__ attHp,
    const _Float16* __restrict__ wLhap, const _Float16* __restrict__ wLhlp,
    const _Float16* __restrict__ Weffp, const float* __restrict__ biasL2,
    const _Float16* __restrict__ w1fp,
    const float* __restrict__ a1w2, const float* __restrict__ a1b2,
    const float* __restrict__ a2w2, const float* __restrict__ a2b2,
    const float* __restrict__ tw1, const float* __restrict__ tb1,
    unsigned short* __restrict__ h_hist)
{
    const int tid = threadIdx.x;
    const int rb0 = blockIdx.x*2;             // rows rb0, rb0+1

    __shared__ float gbuf[2][256];
    __shared__ __align__(16) _Float16 hl16[2][64];
    __shared__ __align__(16) _Float16 ha16[2][64];
    __shared__ __align__(16) _Float16 u16v[2][32];
    __shared__ float hpart[2][64];
    __shared__ float sbuf[2][2][32];
    __shared__ float att8s[2][8];
    __shared__ __align__(16) float preS[2][2][25][36];   // stride 36: bank spread
    __shared__ float memS[2][200];
    __shared__ __align__(16) _Float16 w1fS[64*72];       // stride 72 f16
    __shared__ float tw1T[256];                          // transposed [8][32]
    __shared__ float w2S[2][32];
    __shared__ float b2S[2];
    __shared__ int   tokS[2][NSTEP];

    // ---- one-time block init
    for (int i=tid;i<2*NSTEP;i+=256){ int r=i/NSTEP, s=i-r*NSTEP; tokS[r][s]=inst[(rb0+r)*TT+s]; }
    for (int i=tid;i<3200;i+=256){
        int r = i/1600, rem = i - r*1600, h = rem/800, rem2 = rem - h*800, n = rem2>>5, k = rem2&31;
        preS[r][h][n][k] = (h ? pre2 : pre1)[(size_t)((rb0+r)*NOBJ+n)*32 + k];
    }
    for (int i=tid;i<400;i+=256){
        int r = i/200, rem = i - r*200;
        memS[r][rem] = (rem<100 ? diff : prev)[(size_t)(rb0+r)*100 + (rem%100)];
    }
    for (int i=tid;i<4096;i+=256){
        int rw = i>>6, k = i&63;
        w1fS[rw*72+k] = w1fp[i];
    }
    { int m = tid&31, k = tid>>5; tw1T[k*32+m] = tw1[m*8+k]; }   // all 256 threads
    if (tid<64) w2S[tid>>5][tid&31] = (tid<32 ? a1w2 : a2w2)[tid&31];
    if (tid<2)  b2S[tid] = tid ? a2b2[0] : a1b2[0];
    for (int i=tid;i<128;i+=256){ hl16[i>>6][i&63]=(_Float16)0.f; ha16[i>>6][i&63]=(_Float16)0.f; }

    // ---- weight registers (row = tid of each matrix, shared by both rows)
    h8 wAL[8], wAH[8], wLHa[8], wLHl[8], wEf[4];
    {
        const h8* p0 = (const h8*)(attLp + (size_t)tid*64);
        const h8* p1 = (const h8*)(attHp + (size_t)tid*64);
        const h8* p2 = (const h8*)(wLhap + (size_t)tid*64);
        const h8* p3 = (const h8*)(wLhlp + (size_t)tid*64);
        const h8* p4 = (const h8*)(Weffp + (size_t)tid*32);
        #pragma unroll
        for (int k=0;k<8;++k){ wAL[k]=p0[k]; wAH[k]=p1[k]; wLHa[k]=p2[k]; wLHl[k]=p3[k]; }
        #pragma unroll
        for (int k=0;k<4;++k) wEf[k]=p4[k];
    }
    const float biasv = biasL2[tid];
    const float tb1v  = ((tid&63) < 32) ? tb1[tid&63] : 0.f;
    float c_att = 0.f, c_lang = 0.f;
    __syncthreads();

    const int wave = tid>>6, lane = tid&63;

    const h8* xh0 = (const h8*)&hl16[0][0];
    const h8* xh1 = (const h8*)&hl16[1][0];
    const h8* xa0 = (const h8*)&ha16[0][0];
    const h8* xa1 = (const h8*)&ha16[1][0];
    const h8* xu0 = (const h8*)&u16v[0][0];
    const h8* xu1 = (const h8*)&u16v[1][0];

    // initial embW gather (consumed at t=0; later iterations prefetched)
    float ew0 = embW[(size_t)tokS[0][0]*256 + tid];
    float ew1 = embW[(size_t)tokS[1][0]*256 + tid];

    #pragma unroll 1
    for (int t=0;t<NSTEP;++t){
        // ---- P1: att gates (both rows) + lang hl-partial
        float a0 = ew0, a1 = ew1, p0 = biasv, p1 = biasv;
        {   // prefetch next step's embW row (stays in flight across the
            // lgkm-only barriers; consumed at the top of the next iteration)
            int tn = (t+1 < NSTEP) ? t+1 : NSTEP-1;
            ew0 = embW[(size_t)tokS[0][tn]*256 + tid];
            ew1 = embW[(size_t)tokS[1][tn]*256 + tid];
        }
        #pragma unroll
        for (int k=0;k<8;++k){
            h8 h0 = xh0[k], h1 = xh1[k];
            a0 = dot8(wAL[k],  h0, a0);  a1 = dot8(wAL[k],  h1, a1);
            p0 = dot8(wLHl[k], h0, p0);  p1 = dot8(wLHl[k], h1, p1);
        }
        #pragma unroll
        for (int k=0;k<8;++k){
            h8 v0 = xa0[k], v1 = xa1[k];
            a0 = dot8(wAH[k], v0, a0);   a1 = dot8(wAH[k], v1, a1);
        }
        gbuf[0][tid] = a0; gbuf[1][tid] = a1;
        block_sync_lds();                                    // B1

        // ---- P2: per-row attention serial section (wave r = row r).
        // Stages chain through LDS; DS ops of one wave execute in program
        // order, and every consumer reads the same array its producer wrote
        // (may-alias), so no block barrier is needed inside.
        if (wave < 2){
            const int r = wave;
            // att LSTM update
            float gi = gbuf[r][lane], gf = gbuf[r][64+lane];
            float gg = gbuf[r][128+lane], go = gbuf[r][192+lane];
            float i_=sigf(gi), f_=sigf(gf), g_=tanh_(gg), o_=sigf(go);
            c_att = f_*c_att + i_*g_;
            ha16[r][lane] = (_Float16)(o_*tanh_(c_att));
            // h-projection: hp[lane] = w1f[lane] . ha
            {
                const h8* xa = (const h8*)&ha16[r][0];
                const h8* wr = (const h8*)&w1fS[lane*72];
                float hp = 0.f;
                #pragma unroll
                for (int k=0;k<8;++k) hp = dot8(wr[k], xa[k], hp);
                hpart[r][lane] = hp;
            }
            // scores: 2 heads x 25 objects
            {
                int half = lane>>5, n = lane&31;
                if (n < NOBJ){
                    const float4* pp = (const float4*)&preS[r][half][n][0];
                    const float*  hp = &hpart[r][half*32];
                    const float*  w2 = &w2S[half][0];
                    float a = b2S[half];
                    #pragma unroll
                    for (int i=0;i<8;++i){
                        float4 pv = pp[i];
                        a += fmaxf(hp[4*i+0]+pv.x,0.f)*w2[4*i+0]
                           + fmaxf(hp[4*i+1]+pv.y,0.f)*w2[4*i+1]
                           + fmaxf(hp[4*i+2]+pv.z,0.f)*w2[4*i+2]
                           + fmaxf(hp[4*i+3]+pv.w,0.f)*w2[4*i+3];
                    }
                    sbuf[r][half][n] = a;
                }
            }
            // softmax over 25 + weighted memory sum (lanes 0..7)
            if (lane < 8){
                int half = lane>>2, d = lane&3;
                const float* ss  = &sbuf[r][half][0];
                const float* mem = &memS[r][half*100];
                float m = -1e30f;
                for (int n=0;n<NOBJ;++n) m = fmaxf(m, ss[n]);
                float s=0.f, a=0.f;
                for (int n=0;n<NOBJ;++n){ float e=__expf(ss[n]-m); s+=e; a+=e*mem[n*4+d]; }
                att8s[r][lane] = a/s;
            }
            // trans stage 1 (lanes 0..31)
            if (lane < 32){
                float u = tb1v;
                #pragma unroll
                for (int i=0;i<8;++i) u += att8s[r][i]*tw1T[i*32+lane];
                u16v[r][lane] = (_Float16)fmaxf(u, 0.f);
            }
        }
        block_sync_lds();                                    // B2

        // ---- P3: lang LSTM gates (both rows; tw2 folded into Weff)
        #pragma unroll
        for (int k=0;k<4;++k){
            h8 u0 = xu0[k], u1 = xu1[k];
            p0 = dot8(wEf[k], u0, p0);   p1 = dot8(wEf[k], u1, p1);
        }
        #pragma unroll
        for (int k=0;k<8;++k){
            h8 v0 = xa0[k], v1 = xa1[k];
            p0 = dot8(wLHa[k], v0, p0);  p1 = dot8(wLHa[k], v1, p1);
        }
        gbuf[0][tid] = p0; gbuf[1][tid] = p1;
        block_sync_lds();                                    // B3

        // ---- P4: lang LSTM update + h_hist store (wave r = row r)
        if (wave < 2){
            const int r = wave;
            float gi = gbuf[r][lane], gf = gbuf[r][64+lane];
            float gg = gbuf[r][128+lane], go = gbuf[r][192+lane];
            float i_=sigf(gi), f_=sigf(gf), g_=tanh_(gg), o_=sigf(go);
            c_lang = f_*c_lang + i_*g_;
            float hL = o_*tanh_(c_lang);
            hl16[r][lane] = (_Float16)hL;
            h_hist[((size_t)(rb0+r)*NSTEP + t)*64 + lane] = bf16r(hL);
        }
        block_sync_lds();                                    // B4
    }
}

// ---------------------------------------------------------------- fc + log_softmax

__global__ __launch_bounds__(256) void k_fc(const unsigned short* __restrict__ h_hist,
                                            const unsigned short* __restrict__ fragB,
                                            const float* __restrict__ fcb,
                                            float* __restrict__ out)
{
    const int tid = threadIdx.x;
    const int w = tid >> 6, lane = tid & 63;
    const int q = lane >> 4, l16 = lane & 15;
    const int rowbase = blockIdx.x*16;

    const short8 a0 = *(const short8*)(h_hist + (size_t)(rowbase + l16)*64 + q*8);
    const short8 a1 = *(const short8*)(h_hist + (size_t)(rowbase + l16)*64 + 32 + q*8);

    float m[4], s[4];
    #pragma unroll
    for (int i=0;i<4;++i){ m[i] = -INFINITY; s[i] = 0.f; }

    for (int tile = w; tile < NTILE; tile += 4){
        const short8 b0 = *(const short8*)(fragB + (size_t)((tile*2+0)*64 + lane)*8);
        const short8 b1 = *(const short8*)(fragB + (size_t)((tile*2+1)*64 + lane)*8);
        f32x4 acc = {0.f,0.f,0.f,0.f};
        acc = __builtin_amdgcn_mfma_f32_16x16x32_bf16(a0, b0, acc, 0, 0, 0);
        acc = __builtin_amdgcn_mfma_f32_16x16x32_bf16(a1, b1, acc, 0, 0, 0);
        float bias = fcb[tile*16 + l16];
        #pragma unroll
        for (int i=0;i<4;++i){
            float v = acc[i] + bias;
            float nm = fmaxf(m[i], v);
            s[i] = s[i]*__expf(m[i]-nm) + __expf(v-nm);
            m[i] = nm;
        }
    }
    #pragma unroll
    for (int i=0;i<4;++i){
        #pragma unroll
        for (int off=1; off<16; off<<=1){
            float om = __shfl_xor(m[i], off, 64);
            float os = __shfl_xor(s[i], off, 64);
            float nm = fmaxf(m[i], om);
            s[i] = s[i]*__expf(m[i]-nm) + os*__expf(om-nm);
            m[i] = nm;
        }
    }
    __shared__ float lm[4][16], ls[4][16], fm[16], fl[16];
    if (l16 == 0){
        #pragma unroll
        for (int i=0;i<4;++i){ lm[w][q*4+i] = m[i]; ls[w][q*4+i] = s[i]; }
    }
    __syncthreads();
    if (tid < 16){
        float M = -INFINITY, S = 0.f;
        #pragma unroll
        for (int ww=0;ww<4;++ww){
            float om = lm[ww][tid], os = ls[ww][tid];
            float nm = fmaxf(M, om);
            S = S*__expf(M-nm) + os*__expf(om-nm);
            M = nm;
        }
        fm[tid] = M; fl[tid] = __logf(S);
    }
    __syncthreads();
    float Mr[4], Lr[4];
    #pragma unroll
    for (int i=0;i<4;++i){ Mr[i] = fm[q*4+i]; Lr[i] = fl[q*4+i]; }

    for (int tile = w; tile < NTILE; tile += 4){
        const short8 b0 = *(const short8*)(fragB + (size_t)((tile*2+0)*64 + lane)*8);
        const short8 b1 = *(const short8*)(fragB + (size_t)((tile*2+1)*64 + lane)*8);
        f32x4 acc = {0.f,0.f,0.f,0.f};
        acc = __builtin_amdgcn_mfma_f32_16x16x32_bf16(a0, b0, acc, 0, 0, 0);
        acc = __builtin_amdgcn_mfma_f32_16x16x32_bf16(a1, b1, acc, 0, 0, 0);
        int col = tile*16 + l16;
        if (col < VOC){
            float bias = fcb[col];
            #pragma unroll
            for (int i=0;i<4;++i)
                out[(size_t)(rowbase + q*4 + i)*VOC + col] = acc[i] + bias - Mr[i] - Lr[i];
        }
    }
}

// ---------------------------------------------------------------- launcher

extern "C" void kernel_launch(void* const* d_in, const int* in_sizes, int n_in,
                              void* d_out, int out_size, void* d_ws, size_t ws_size,
                              hipStream_t stream)
{
    const int*   inst  = (const int*)  d_in[0];
    const float* prev  = (const float*)d_in[1];
    const float* fin   = (const float*)d_in[2];
    const float* embed = (const float*)d_in[3];
    const float* Wia   = (const float*)d_in[4];
    const float* Wha   = (const float*)d_in[5];
    const float* bia   = (const float*)d_in[6];
    const float* bha   = (const float*)d_in[7];
    const float* Wil   = (const float*)d_in[8];
    const float* Whl   = (const float*)d_in[9];
    const float* bil   = (const float*)d_in[10];
    const float* bhl   = (const float*)d_in[11];
    const float* fcw   = (const float*)d_in[12];
    const float* fcbi  = (const float*)d_in[13];
    const float* a1w1  = (const float*)d_in[14];
    const float* a1b1  = (const float*)d_in[15];
    const float* a1w2  = (const float*)d_in[16];
    const float* a1b2  = (const float*)d_in[17];
    const float* a2w1  = (const float*)d_in[18];
    const float* a2b1  = (const float*)d_in[19];
    const float* a2w2  = (const float*)d_in[20];
    const float* a2b2  = (const float*)d_in[21];
    const float* tw1   = (const float*)d_in[22];
    const float* tb1   = (const float*)d_in[23];
    const float* tw2   = (const float*)d_in[24];
    const float* tb2   = (const float*)d_in[25];
    float* out = (float*)d_out;

    char* wsb = (char*)d_ws; size_t off = 0;
    auto alloc = [&](size_t bytes)->char*{
        char* p = wsb + off; off = (off + bytes + 511) & ~(size_t)511; return p;
    };
    float*          embW  = (float*)alloc((size_t)VOC*256*4);
    float*          diff  = (float*)alloc((size_t)BATCH*NOBJ*4*4);
    float*          pre1  = (float*)alloc((size_t)BATCH*NOBJ*32*4);
    float*          pre2  = (float*)alloc((size_t)BATCH*NOBJ*32*4);
    _Float16*       attLp = (_Float16*)alloc((size_t)256*64*2);
    _Float16*       attHp = (_Float16*)alloc((size_t)256*64*2);
    _Float16*       wLhap = (_Float16*)alloc((size_t)256*64*2);
    _Float16*       wLhlp = (_Float16*)alloc((size_t)256*64*2);
    _Float16*       Weffp = (_Float16*)alloc((size_t)256*32*2);
    _Float16*       w1fp  = (_Float16*)alloc((size_t)64*64*2);
    float*          biasL2= (float*)alloc(256*4);
    float*          fcb   = (float*)alloc((size_t)NPAD*4);
    unsigned short* hhist = (unsigned short*)alloc((size_t)NROWS*64*2);
    unsigned short* fragB = (unsigned short*)alloc((size_t)NTILE*2*64*8*2);

    // prep
    k_pre    <<<(BATCH*NOBJ+255)/256, 256, 0, stream>>>(prev, fin, a1w1, a1b1, a2w1, a2b1, diff, pre1, pre2);
    k_embw   <<<VOC, 256, 0, stream>>>(embed, Wia, bia, bha, embW);
    k_packrow<<<64, 256, 0, stream>>>(Wia, attLp, 128, 0,  64, 256*64);   // W_ih_att[:, :64]  (h_lang)
    k_packrow<<<64, 256, 0, stream>>>(Wha, attHp,  64, 0,  64, 256*64);   // W_hh_att          (h_att)
    k_packrow<<<64, 256, 0, stream>>>(Wil, wLhap, 128, 64, 64, 256*64);   // W_ih_lang[:,64:]  (h_att)
    k_packrow<<<64, 256, 0, stream>>>(Whl, wLhlp,  64, 0,  64, 256*64);   // W_hh_lang         (h_lang)
    k_packrow<<<8,  256, 0, stream>>>(a1w1, w1fp,       68, 0, 64, 32*64);// att1 w1[:, :64]
    k_packrow<<<8,  256, 0, stream>>>(a2w1, w1fp+32*64, 68, 0, 64, 32*64);// att2 w1[:, :64]
    k_weff   <<<1, 256, 0, stream>>>(Wil, tw2, tb2, bil, bhl, Weffp, biasL2);
    k_fcbpad <<<(NPAD+255)/256, 256, 0, stream>>>(fcbi, fcb);
    k_fragb  <<<63, 256, 0, stream>>>(fcw, fragB);

    // recurrent scan: 2 batch rows per block
    k_recur<<<BATCH/2, 256, 0, stream>>>(inst, embW, diff, prev, pre1, pre2,
                                         attLp, attHp, wLhap, wLhlp, Weffp, biasL2, w1fp,
                                         a1w2, a1b2, a2w2, a2b2, tw1, tb1, hhist);

    // big projection + log_softmax
    k_fc<<<NROWS/16, 256, 0, stream>>>(hhist, fragB, fcb, out);
}